// Round 8
// baseline (171.756 us; speedup 1.0000x reference)
//
#include <hip/hip_runtime.h>
#include <math.h>

#define H_ 56
#define W_ 56
#define CIN 256
#define COUT 256
#define NB 8
#define SPIX 3136
#define KG 2304
#define MTOT 25088
#define MT 64
#define NBLK2 392  // MTOT / 64 = 8 XCDs x 49 (one image per XCD)
#define GUARD_PX 2048                 // 1 MB guard each side of xb (512 B/px)

typedef _Float16 v8hf __attribute__((ext_vector_type(8)));
typedef float    v4f  __attribute__((ext_vector_type(4)));

#define WAIT_VM(N)  do { asm volatile("s_waitcnt vmcnt(" #N ")" ::: "memory"); \
                         __builtin_amdgcn_sched_barrier(0); } while (0)
#define WAIT_LGKM0  do { asm volatile("s_waitcnt lgkmcnt(0)" ::: "memory"); \
                         __builtin_amdgcn_sched_barrier(0); } while (0)
#define BARR        do { asm volatile("s_barrier" ::: "memory"); } while (0)

// ---------- merged pre-kernel: z<8: NCHW fp32 -> NHWC f16 (image z)
//            z==8: weight (Cout,Cin,3,3) -> Bp[o][tap*256+c] f16
//            z==9: zero the two 1MB guard bands around xb
__global__ __launch_bounds__(256) void prep_xw(const float* __restrict__ x,
                                               const float* __restrict__ w,
                                               _Float16* __restrict__ xb,
                                               _Float16* __restrict__ bp) {
    __shared__ float tile[64][65];
    const int tid = threadIdx.x;
    if (blockIdx.z < 8) {
        const int n = blockIdx.z, c0 = blockIdx.y * 64, s0 = blockIdx.x * 64;
        const float* xp = x + (size_t)n * CIN * SPIX;
        _Float16* xo = xb + (size_t)n * SPIX * CIN;
#pragma unroll
        for (int i = 0; i < 16; ++i) {
            int idx = tid + i * 256;
            int cr = idx >> 6, sc = idx & 63;
            tile[cr][sc] = xp[(c0 + cr) * SPIX + s0 + sc];
        }
        __syncthreads();
#pragma unroll
        for (int i = 0; i < 16; ++i) {
            int idx = tid + i * 256;
            int sr = idx >> 6, cc = idx & 63;
            xo[(s0 + sr) * CIN + c0 + cc] = (_Float16)tile[cc][sr];
        }
    } else if (blockIdx.z == 8) {
        const int base = (blockIdx.y * 49 + blockIdx.x) * 256 + tid;
        for (int i = base; i < COUT * KG; i += 196 * 256) {
            const int o = i / KG;
            const int rem = i - o * KG;
            const int c = rem / 9;
            const int tap = rem - c * 9;
            bp[(size_t)o * KG + tap * 256 + c] = (_Float16)w[i];
        }
    } else {
        const int gtid = (blockIdx.y * 49 + blockIdx.x) * 256 + tid;
        v8hf* lo = (v8hf*)(xb - (size_t)GUARD_PX * CIN);
        v8hf* hi = (v8hf*)(xb + (size_t)NB * SPIX * CIN);
        const v8hf z = (v8hf)(_Float16)0.f;
        for (int i = gtid; i < 65536; i += 196 * 256) {
            lo[i] = z;
            hi[i] = z;
        }
    }
}

// ---------- bilinear params for ALL 9 taps of this block's 64 px.
// Base UNCLAMPED (corner reads are base-relative); weight-0 corners read
// into zeroed guard bands. Safety clamp only fires when all weights 0.
__device__ __forceinline__ void compute_params(
    const float* __restrict__ offs, const float* __restrict__ msk,
    int m0, int* sS, float4* sW, int tid)
{
    for (int idx = tid; idx < 9 * MT; idx += 256) {
        const int tl = idx >> 6, pl = idx & 63;
        const int pg = m0 + pl;
        const int n  = pg / SPIX;
        const int s  = pg - n * SPIX;
        const int h  = s / W_, w = s - h * W_;
        const int kY = tl / 3, kX = tl - kY * 3;
        const float dy = offs[n * (18 * SPIX) + (2 * tl) * SPIX + s];
        const float dx = offs[n * (18 * SPIX) + (2 * tl + 1) * SPIX + s];
        const float mk = msk[n * (9 * SPIX) + tl * SPIX + s];
        const float py = dy + (float)(kY + h - 1);   // PAD=1,STRIDE=1,DIL=1
        const float px = dx + (float)(kX + w - 1);
        const float fy0 = floorf(py), fx0 = floorf(px);
        const int y0 = (int)fy0, x0 = (int)fx0;
        const float wy1 = py - fy0, wx1 = px - fx0;
        const float wy0 = 1.f - wy1, wx0 = 1.f - wx1;
        const bool yv0 = (y0 >= 0) & (y0 < H_);
        const bool yv1 = (y0 + 1 >= 0) & (y0 + 1 < H_);
        const bool xv0 = (x0 >= 0) & (x0 < W_);
        const bool xv1 = (x0 + 1 >= 0) & (x0 + 1 < W_);
        float4 wt;
        wt.x = (yv0 & xv0) ? wy0 * wx0 * mk : 0.f;
        wt.y = (yv0 & xv1) ? wy0 * wx1 * mk : 0.f;
        wt.z = (yv1 & xv0) ? wy1 * wx0 * mk : 0.f;
        wt.w = (yv1 & xv1) ? wy1 * wx1 * mk : 0.f;
        int base = n * SPIX + y0 * W_ + x0;
        base = min(max(base, -GUARD_PX), NB * SPIX - 58 + GUARD_PX);
        sS[idx] = base * CIN;
        sW[idx] = wt;
    }
}

// ---------- fused deformable-gather + f16 MFMA GEMM (v8: 2-blocks/CU TLP).
// Block = 64 px x 256 out, 4 waves (256 thr); grid 392 = 8 XCD x 49 (one
// image per XCD). B-frags read DIRECT from L2 into ping-pong reg sets,
// prefetched one iter ahead (counted vmcnt, no drain) -> no B LDS. LDS =
// A dbuf 16KB + params 11.5KB = 28KB -> 2 independent blocks/CU: while one
// block sits in its memory clump, the other MFMAs (the overlap v7 proved
// impossible within one barrier domain).
// vmcnt ledger (queue at iter entry = [G(ks+1) 8, B(ks+1) 8]):
//   LOAD_AFR ; vmcnt(8)->G(ks+1) ; combine->A[nxt] ; gather G(ks+2) ;
//   vmcnt(8)->B(ks+1) ; MFMA(A[cur],Bset[ks&1]) ; issue B(ks+2)->set[ks&1];
//   lgkmcnt(0) ; s_barrier.   Pair-unrolled so all reg indices are static.
__global__ __launch_bounds__(256, 2) void mdcn_fused8(
    const _Float16* __restrict__ xb,   // NHWC f16 (1MB zeroed guard both sides)
    const float*    __restrict__ offs,
    const float*    __restrict__ msk,
    const _Float16* __restrict__ bp,   // [COUT][KG] tap-major K
    const float*    __restrict__ bias,
    float*          __restrict__ out)
{
    __shared__ __align__(16) char smem[28160];
    _Float16* A0 = (_Float16*)smem;                 // [64 px][64 k] swizzled
    _Float16* A1 = (_Float16*)(smem + 8192);
    int*      sS = (int*)(smem + 16384);            // [9*64]
    float4*   sW = (float4*)(smem + 18688);         // [9*64]

    const int tid  = threadIdx.x;
    const int lane = tid & 63, wv = tid >> 6;       // 4 waves, wave owns 64 out
    const int l15 = lane & 15, q = lane >> 4;

    // XCD swizzle: 392 = 8 * 49 exactly; each XCD -> 49 blocks = one image
    const int wg = (blockIdx.x & 7) * 49 + (blockIdx.x >> 3);
    const int m0 = wg * MT;

    compute_params(offs, msk, m0, sS, sW, tid);

    v4f acc[4][4];
#pragma unroll
    for (int i = 0; i < 4; ++i)
#pragma unroll
        for (int j = 0; j < 4; ++j) acc[i][j] = (v4f)0.f;

    __syncthreads();                                // params visible (once)

    const int pxl = tid >> 2, c2 = tid & 3;         // pixel row, chunk pair
    v8hf ga0, ga1, ga2, ga3, gb0, gb1, gb2, gb3;
    float4 cw;
    v8hf afr[2][4];                                 // A frags [kf][mt]
    v8hf B0r[8], B1r[8];                            // B reg sets (static idx)

#define GATHER(E, KQ)                                                   \
    { const int e_ = (E);                                               \
      const int b_ = sS[e_] + ((KQ) << 6) + c2 * 8;                     \
      cw  = sW[e_];                                                     \
      ga0 = *(const v8hf*)(xb + b_);                                    \
      ga1 = *(const v8hf*)(xb + b_ + 256);                              \
      ga2 = *(const v8hf*)(xb + b_ + 14336);                            \
      ga3 = *(const v8hf*)(xb + b_ + 14592);                            \
      gb0 = *(const v8hf*)(xb + b_ + 32);                               \
      gb1 = *(const v8hf*)(xb + b_ + 288);                              \
      gb2 = *(const v8hf*)(xb + b_ + 14368);                            \
      gb3 = *(const v8hf*)(xb + b_ + 14624); }

#define COMBINE_STORE(AP)                                               \
    { const _Float16 wx_ = (_Float16)cw.x, wy_ = (_Float16)cw.y;        \
      const _Float16 wz_ = (_Float16)cw.z, ww_ = (_Float16)cw.w;        \
      v8hf r0_ = ga0 * wx_ + ga1 * wy_ + ga2 * wz_ + ga3 * ww_;         \
      v8hf r1_ = gb0 * wx_ + gb1 * wy_ + gb2 * wz_ + gb3 * ww_;         \
      *(v8hf*)((AP) + pxl * 64 + (((c2)     ^ (pxl & 7)) << 3)) = r0_;  \
      *(v8hf*)((AP) + pxl * 64 + (((c2 + 4) ^ (pxl & 7)) << 3)) = r1_; }

#define ISSUE_B(KS, BR)                                                 \
    { _Pragma("unroll")                                                 \
      for (int i = 0; i < 8; ++i) {                                     \
        const int kf_ = i >> 2, nt_ = i & 3;                            \
        BR[i] = *(const v8hf*)(bp                                       \
            + (size_t)(wv * 64 + nt_ * 16 + l15) * KG                   \
            + (KS) * 64 + (kf_ * 4 + q) * 8); } }

#define LOAD_AFR(AB)                                                    \
    { _Pragma("unroll")                                                 \
      for (int kf = 0; kf < 2; ++kf)                                    \
        _Pragma("unroll")                                               \
        for (int mt = 0; mt < 4; ++mt) {                                \
          const int row = mt * 16 + l15;                                \
          const int pch = (kf * 4 + q) ^ (row & 7);                     \
          afr[kf][mt] = *(const v8hf*)((AB) + row * 64 + pch * 8); } }

#define MFMA_EXEC(BR)                                                   \
    { __builtin_amdgcn_s_setprio(1);                                    \
      _Pragma("unroll")                                                 \
      for (int kf = 0; kf < 2; ++kf)                                    \
        _Pragma("unroll")                                               \
        for (int mt = 0; mt < 4; ++mt)                                  \
          _Pragma("unroll")                                             \
          for (int nt = 0; nt < 4; ++nt)                                \
            acc[mt][nt] = __builtin_amdgcn_mfma_f32_16x16x32_f16(       \
                afr[kf][mt], BR[kf * 4 + nt], acc[mt][nt], 0, 0, 0);    \
      __builtin_amdgcn_s_setprio(0); }

    // ---------- prologue: queue must end as [G(1) 8, B(1) 8]
    ISSUE_B(0, B0r);                   // B(0) -> set0
    GATHER(pxl, 0)                     // G(0): tap 0, kq 0
    WAIT_VM(0);                        // both ready (one-time drain)
    COMBINE_STORE(A0)                  // A[0]
    GATHER(pxl, 1)                     // G(1): tap 0, kq 1
    ISSUE_B(1, B1r);                   // B(1) -> set1
    WAIT_LGKM0;                        // A0 writes visible
    BARR;

#pragma unroll 1
    for (int k2 = 0; k2 < 17; ++k2) {
        const int e = k2 * 2;                       // even iter 0..32
        LOAD_AFR(A0);
        WAIT_VM(8);                                 // G(e+1) regs ready
        COMBINE_STORE(A1)                           // A[e+1]
        GATHER(((e + 2) >> 2) * MT + pxl, (e + 2) & 3)   // G(e+2)
        WAIT_VM(8);                                 // B(e+1) ready (G(e+2) flies)
        MFMA_EXEC(B0r);                             // A[e] x B(e)
        ISSUE_B(e + 2, B0r);                        // B(e+2) -> set0
        WAIT_LGKM0;
        BARR;

        const int o = e + 1;                        // odd iter 1..33
        LOAD_AFR(A1);
        WAIT_VM(8);                                 // G(o+1)
        COMBINE_STORE(A0)                           // A[o+1]
        GATHER(((o + 2) >> 2) * MT + pxl, (o + 2) & 3)   // G(o+2)
        WAIT_VM(8);                                 // B(o+1)
        MFMA_EXEC(B1r);                             // A[o] x B(o)
        ISSUE_B(o + 2, B1r);                        // B(o+2) -> set1
        WAIT_LGKM0;
        BARR;
    }

    // ---------- tail: iters 34, 35 (no further issues)
    LOAD_AFR(A0);
    WAIT_VM(8);                        // G(35)
    COMBINE_STORE(A1)                  // A[35]
    WAIT_VM(0);                        // B(35)
    MFMA_EXEC(B0r);                    // iter 34
    WAIT_LGKM0;
    BARR;
    LOAD_AFR(A1);
    MFMA_EXEC(B1r);                    // iter 35

#undef GATHER
#undef COMBINE_STORE
#undef ISSUE_B
#undef LOAD_AFR
#undef MFMA_EXEC

    // ---- epilogue: per-wave LDS transpose (wave-local region)
    WAIT_LGKM0;
    BARR;                              // all frag reads of smem done
    float* epi = (float*)smem + wv * 1104;          // 64 x 17 floats per wave
    const int pg_l = m0 + lane;        // 64-px block: lane = pixel
    const int n_l  = pg_l / SPIX;
    float* outp = out + (size_t)n_l * (COUT * SPIX) + (pg_l - n_l * SPIX);

#pragma unroll
    for (int nt = 0; nt < 4; ++nt) {
        const float bv = bias[wv * 64 + nt * 16 + l15];
#pragma unroll
        for (int mt = 0; mt < 4; ++mt)
#pragma unroll
            for (int r = 0; r < 4; ++r)
                epi[(mt * 16 + q * 4 + r) * 17 + l15] = acc[mt][nt][r] + bv;
#pragma unroll
        for (int oc = 0; oc < 16; ++oc)
            outp[(size_t)(wv * 64 + nt * 16 + oc) * SPIX] = epi[lane * 17 + oc];
    }
}

// ---------- fp32 fallback (round-1 verified, no workspace)
#define BM 64
#define BN 64
#define BKF 32
#define AST 68
#define BST 68
#define CST 65
__global__ __launch_bounds__(256) void mdcn_fallback(
    const float* __restrict__ xs, const float* __restrict__ offs,
    const float* __restrict__ msk, const float* __restrict__ wraw,
    const float* __restrict__ bias, float* __restrict__ out)
{
    __shared__ float smem[BKF * AST + BKF * BST];
    __shared__ int   sBase[4][BM];
    __shared__ float sWgt[4][BM];
    float (*At)[AST] = (float (*)[AST])smem;
    float (*Bt)[BST] = (float (*)[BST])(smem + BKF * AST);
    float (*Cs)[CST] = (float (*)[CST])smem;
    const int tid = threadIdx.x;
    const int m0 = blockIdx.x * BM;
    const int o0 = blockIdx.y * BN;
    const int n  = m0 / SPIX;
    const int s0 = m0 - n * SPIX;
    const int tx = tid & 15, ty = tid >> 4;
    float acc[4][4] = {};
    for (int k = 0; k < 9; ++k) {
        if (tid < BM) {
            const int s = s0 + tid;
            const int h = s / W_;
            const int w = s - h * W_;
            const int kY = k / 3, kX = k - kY * 3;
            const float dy = offs[(size_t)n * (18 * SPIX) + (size_t)(2 * k) * SPIX + s];
            const float dx = offs[(size_t)n * (18 * SPIX) + (size_t)(2 * k + 1) * SPIX + s];
            const float mk = msk[(size_t)n * (9 * SPIX) + (size_t)k * SPIX + s];
            const float py = dy + (float)(kY + h - 1);
            const float px = dx + (float)(kX + w - 1);
            const float fy0 = floorf(py), fx0 = floorf(px);
            const int y0 = (int)fy0, x0 = (int)fx0;
            const float wy1 = py - fy0, wx1 = px - fx0;
            const float wy0 = 1.0f - wy1, wx0 = 1.0f - wx1;
#pragma unroll
            for (int t = 0; t < 4; ++t) {
                const int yi = y0 + (t >> 1), xi = x0 + (t & 1);
                const bool valid = (yi >= 0) & (yi < H_) & (xi >= 0) & (xi < W_);
                const int yc = min(max(yi, 0), H_ - 1);
                const int xc = min(max(xi, 0), W_ - 1);
                float wt = ((t >> 1) ? wy1 : wy0) * ((t & 1) ? wx1 : wx0) * mk;
                sBase[t][tid] = n * (CIN * SPIX) + yc * W_ + xc;
                sWgt[t][tid] = valid ? wt : 0.0f;
            }
        }
        __syncthreads();
        for (int c0 = 0; c0 < CIN; c0 += BKF) {
#pragma unroll
            for (int i = 0; i < 8; ++i) {
                int idx = tid + i * 256;
                int row = idx >> 5, cc = idx & 31;
                int ce = (c0 + cc) * SPIX;
                At[cc][row] = sWgt[0][row] * xs[sBase[0][row] + ce]
                            + sWgt[1][row] * xs[sBase[1][row] + ce]
                            + sWgt[2][row] * xs[sBase[2][row] + ce]
                            + sWgt[3][row] * xs[sBase[3][row] + ce];
            }
#pragma unroll
            for (int i = 0; i < 8; ++i) {
                int idx = tid + i * 256;
                int kf = idx >> 6, o = idx & 63;
                Bt[kf][o] = wraw[(size_t)(o0 + o) * KG + (c0 + kf) * 9 + k];
            }
            __syncthreads();
#pragma unroll
            for (int kf = 0; kf < BKF; ++kf) {
                const float4 a = *(const float4*)&At[kf][ty * 4];
                const float4 b = *(const float4*)&Bt[kf][tx * 4];
                acc[0][0] = fmaf(a.x, b.x, acc[0][0]); acc[0][1] = fmaf(a.x, b.y, acc[0][1]);
                acc[0][2] = fmaf(a.x, b.z, acc[0][2]); acc[0][3] = fmaf(a.x, b.w, acc[0][3]);
                acc[1][0] = fmaf(a.y, b.x, acc[1][0]); acc[1][1] = fmaf(a.y, b.y, acc[1][1]);
                acc[1][2] = fmaf(a.y, b.z, acc[1][2]); acc[1][3] = fmaf(a.y, b.w, acc[1][3]);
                acc[2][0] = fmaf(a.z, b.x, acc[2][0]); acc[2][1] = fmaf(a.z, b.y, acc[2][1]);
                acc[2][2] = fmaf(a.z, b.z, acc[2][2]); acc[2][3] = fmaf(a.z, b.w, acc[2][3]);
                acc[3][0] = fmaf(a.w, b.x, acc[3][0]); acc[3][1] = fmaf(a.w, b.y, acc[3][1]);
                acc[3][2] = fmaf(a.w, b.z, acc[3][2]); acc[3][3] = fmaf(a.w, b.w, acc[3][3]);
            }
            __syncthreads();
        }
    }
#pragma unroll
    for (int i = 0; i < 4; ++i)
#pragma unroll
        for (int j = 0; j < 4; ++j)
            Cs[ty * 4 + i][tx * 4 + j] = acc[i][j] + bias[o0 + tx * 4 + j];
    __syncthreads();
    const int pix = tid & 63, ob = tid >> 6;
    float* outp = out + (size_t)n * COUT * SPIX + s0 + pix;
#pragma unroll
    for (int r = 0; r < 16; ++r) {
        int o = r * 4 + ob;
        outp[(size_t)(o0 + o) * SPIX] = Cs[pix][o];
    }
}

extern "C" void kernel_launch(void* const* d_in, const int* in_sizes, int n_in,
                              void* d_out, int out_size, void* d_ws, size_t ws_size,
                              hipStream_t stream) {
    const float* x    = (const float*)d_in[0];
    const float* offs = (const float*)d_in[1];
    const float* msk  = (const float*)d_in[2];
    const float* w    = (const float*)d_in[3];
    const float* bias = (const float*)d_in[4];
    float* out = (float*)d_out;

    const size_t GUARD_B  = (size_t)GUARD_PX * CIN * sizeof(_Float16);  // 1 MB
    const size_t xb_bytes = (size_t)NB * SPIX * CIN * sizeof(_Float16);
    const size_t bp_bytes = (size_t)KG * COUT * sizeof(_Float16);
    const size_t need     = GUARD_B + xb_bytes + GUARD_B + bp_bytes;

    if (ws_size >= need) {
        _Float16* xb = (_Float16*)((char*)d_ws + GUARD_B);
        _Float16* bp = (_Float16*)((char*)d_ws + GUARD_B + xb_bytes + GUARD_B);
        prep_xw<<<dim3(49, 4, 10), 256, 0, stream>>>(x, w, xb, bp);
        mdcn_fused8<<<dim3(NBLK2), 256, 0, stream>>>(xb, offs, msk, bp, bias, out);
    } else {
        mdcn_fallback<<<dim3(MTOT / BM, COUT / BN), 256, 0, stream>>>(
            x, offs, msk, w, bias, out);
    }
}

// Round 9
// 167.945 us; speedup vs baseline: 1.0227x; 1.0227x over previous
//
#include <hip/hip_runtime.h>
#include <math.h>

#define H_ 56
#define W_ 56
#define CIN 256
#define COUT 256
#define NB 8
#define SPIX 3136
#define KG 2304
#define MTOT 25088
#define MT 128
#define NBLK 196   // MTOT / MT
#define GUARD_PX 2048                 // 1 MB guard each side of xb (512 B/px)

typedef _Float16 v8hf __attribute__((ext_vector_type(8)));
typedef float    v4f  __attribute__((ext_vector_type(4)));

#define WAIT_VM(N)  do { asm volatile("s_waitcnt vmcnt(" #N ")" ::: "memory"); \
                         __builtin_amdgcn_sched_barrier(0); } while (0)
#define WAIT_LGKM0  do { asm volatile("s_waitcnt lgkmcnt(0)" ::: "memory"); \
                         __builtin_amdgcn_sched_barrier(0); } while (0)
#define BARR        do { asm volatile("s_barrier" ::: "memory"); } while (0)

__device__ __forceinline__ void async_copy16(const void* g, void* l) {
    __builtin_amdgcn_global_load_lds(
        (const __attribute__((address_space(1))) void*)g,
        (__attribute__((address_space(3))) void*)l, 16, 0, 0);
}

// ---------- merged pre-kernel: z<8: NCHW fp32 -> NHWC f16 (image z)
//            z==8: weight (Cout,Cin,3,3) -> Bp[o][tap*256+c] f16
//            z==9: zero the two 1MB guard bands around xb
__global__ __launch_bounds__(256) void prep_xw(const float* __restrict__ x,
                                               const float* __restrict__ w,
                                               _Float16* __restrict__ xb,
                                               _Float16* __restrict__ bp) {
    __shared__ float tile[64][65];
    const int tid = threadIdx.x;
    if (blockIdx.z < 8) {
        const int n = blockIdx.z, c0 = blockIdx.y * 64, s0 = blockIdx.x * 64;
        const float* xp = x + (size_t)n * CIN * SPIX;
        _Float16* xo = xb + (size_t)n * SPIX * CIN;
#pragma unroll
        for (int i = 0; i < 16; ++i) {
            int idx = tid + i * 256;
            int cr = idx >> 6, sc = idx & 63;
            tile[cr][sc] = xp[(c0 + cr) * SPIX + s0 + sc];
        }
        __syncthreads();
#pragma unroll
        for (int i = 0; i < 16; ++i) {
            int idx = tid + i * 256;
            int sr = idx >> 6, cc = idx & 63;
            xo[(s0 + sr) * CIN + c0 + cc] = (_Float16)tile[cc][sr];
        }
    } else if (blockIdx.z == 8) {
        const int base = (blockIdx.y * 49 + blockIdx.x) * 256 + tid;
        for (int i = base; i < COUT * KG; i += 196 * 256) {
            const int o = i / KG;
            const int rem = i - o * KG;
            const int c = rem / 9;
            const int tap = rem - c * 9;
            bp[(size_t)o * KG + tap * 256 + c] = (_Float16)w[i];
        }
    } else {
        const int gtid = (blockIdx.y * 49 + blockIdx.x) * 256 + tid;
        v8hf* lo = (v8hf*)(xb - (size_t)GUARD_PX * CIN);
        v8hf* hi = (v8hf*)(xb + (size_t)NB * SPIX * CIN);
        const v8hf z = (v8hf)(_Float16)0.f;
        for (int i = gtid; i < 65536; i += 196 * 256) {
            lo[i] = z;
            hi[i] = z;
        }
    }
}

// ---------- bilinear params for ALL 9 taps of this block's 128 px.
// Base UNCLAMPED (corner reads are base-relative); weight-0 corners read
// into zeroed guard bands. Safety clamp only fires when all weights 0.
__device__ __forceinline__ void compute_params(
    const float* __restrict__ offs, const float* __restrict__ msk,
    int m0, int* sS, float4* sW, int tid)
{
    for (int idx = tid; idx < 9 * MT; idx += 512) {
        const int tl = idx >> 7, pl = idx & 127;
        const int pg = m0 + pl;
        const int n  = pg / SPIX;
        const int s  = pg - n * SPIX;
        const int h  = s / W_, w = s - h * W_;
        const int kY = tl / 3, kX = tl - kY * 3;
        const float dy = offs[n * (18 * SPIX) + (2 * tl) * SPIX + s];
        const float dx = offs[n * (18 * SPIX) + (2 * tl + 1) * SPIX + s];
        const float mk = msk[n * (9 * SPIX) + tl * SPIX + s];
        const float py = dy + (float)(kY + h - 1);   // PAD=1,STRIDE=1,DIL=1
        const float px = dx + (float)(kX + w - 1);
        const float fy0 = floorf(py), fx0 = floorf(px);
        const int y0 = (int)fy0, x0 = (int)fx0;
        const float wy1 = py - fy0, wx1 = px - fx0;
        const float wy0 = 1.f - wy1, wx0 = 1.f - wx1;
        const bool yv0 = (y0 >= 0) & (y0 < H_);
        const bool yv1 = (y0 + 1 >= 0) & (y0 + 1 < H_);
        const bool xv0 = (x0 >= 0) & (x0 < W_);
        const bool xv1 = (x0 + 1 >= 0) & (x0 + 1 < W_);
        float4 wt;
        wt.x = (yv0 & xv0) ? wy0 * wx0 * mk : 0.f;
        wt.y = (yv0 & xv1) ? wy0 * wx1 * mk : 0.f;
        wt.z = (yv1 & xv0) ? wy1 * wx0 * mk : 0.f;
        wt.w = (yv1 & xv1) ? wy1 * wx1 * mk : 0.f;
        int base = n * SPIX + y0 * W_ + x0;
        base = min(max(base, -GUARD_PX), NB * SPIX - 58 + GUARD_PX);
        sS[idx] = base * CIN;
        sW[idx] = wt;
    }
}

// ---------- fused deformable-gather + f16 MFMA GEMM (v9: producer/consumer
// wave specialization on the v6 buffers/swizzles).
// 128 px x 256 out, grid 196, 512 thr = 8 waves. Waves 0-3 = PRODUCERS (all
// VMEM: 16 gather loads/thread + 8 B-stage asyncs/wave + combine + A writes).
// Waves 4-7 = CONSUMERS (zero VMEM: 24 ds_reads + 64 MFMAs per iter; tile
// 64px x 128out, acc 4x8). Each SIMD hosts 1 producer + 1 consumer -> TA/VALU
// (producer) co-schedules with LDS-read/MFMA (consumer) = sum -> max (m114).
// One s_barrier per iter; producers write only [nxt], consumers read only
// [cur]; swap at the barrier. Barrier counts: 38 == 38 (prologue + 36 + epi).
// Producer vmcnt ledger: entry [G(ks+1) 16]; +S(ks+1) 8 -> vmcnt(8) retires
// G; combine->A[nxt]; +G(ks+2) 16 -> vmcnt(16) retires S; lgkm0; s_barrier.
__global__ __launch_bounds__(512, 2) void mdcn_fused9(
    const _Float16* __restrict__ xb,   // NHWC f16 (1MB zeroed guard both sides)
    const float*    __restrict__ offs,
    const float*    __restrict__ msk,
    const _Float16* __restrict__ bp,   // [COUT][KG] tap-major K
    const float*    __restrict__ bias,
    float*          __restrict__ out)
{
    __shared__ __align__(16) char smem[121344];
    // A0 @0 (16K) | A1 @16384 | B0 @32768 (32K) | B1 @65536
    int*    sS = (int*)(smem + 98304);              // [9*128]
    float4* sW = (float4*)(smem + 102912);          // [9*128]

    const int tid  = threadIdx.x;
    const int lane = tid & 63, wv = tid >> 6;       // 8 waves
    const int l15 = lane & 15, q = lane >> 4;

    // bijective chunked XCD swizzle: 196 = 8*24 + 4
    const int xcd = blockIdx.x & 7, ib = blockIdx.x >> 3;
    const int wg  = (xcd < 4) ? xcd * 25 + ib : 100 + (xcd - 4) * 24 + ib;
    const int m0  = wg * MT;

    compute_params(offs, msk, m0, sS, sW, tid);
    __syncthreads();                                // params visible (once)

    if (wv < 4) {
        // ================= PRODUCER (waves 0-3, tid 0..255) =================
        const int p2 = tid >> 2, c2 = tid & 3;      // pixel p2 & p2+64, chunk c2
        v8hf gA[8], gB[8];                          // px p2 / px p2+64
        float4 cwA, cwB;

#define GATHER16(TAP, KQ)                                               \
        { const int e0_ = (TAP) * MT + p2;                              \
          const int b0_ = sS[e0_]      + ((KQ) << 6) + c2 * 8;          \
          const int b1_ = sS[e0_ + 64] + ((KQ) << 6) + c2 * 8;          \
          cwA = sW[e0_]; cwB = sW[e0_ + 64];                            \
          gA[0] = *(const v8hf*)(xb + b0_);                             \
          gA[1] = *(const v8hf*)(xb + b0_ + 256);                       \
          gA[2] = *(const v8hf*)(xb + b0_ + 14336);                     \
          gA[3] = *(const v8hf*)(xb + b0_ + 14592);                     \
          gA[4] = *(const v8hf*)(xb + b0_ + 32);                        \
          gA[5] = *(const v8hf*)(xb + b0_ + 288);                       \
          gA[6] = *(const v8hf*)(xb + b0_ + 14368);                     \
          gA[7] = *(const v8hf*)(xb + b0_ + 14624);                     \
          gB[0] = *(const v8hf*)(xb + b1_);                             \
          gB[1] = *(const v8hf*)(xb + b1_ + 256);                       \
          gB[2] = *(const v8hf*)(xb + b1_ + 14336);                     \
          gB[3] = *(const v8hf*)(xb + b1_ + 14592);                     \
          gB[4] = *(const v8hf*)(xb + b1_ + 32);                        \
          gB[5] = *(const v8hf*)(xb + b1_ + 288);                       \
          gB[6] = *(const v8hf*)(xb + b1_ + 14368);                     \
          gB[7] = *(const v8hf*)(xb + b1_ + 14624); }

#define COMBINE16(AP)                                                   \
        { const _Float16 ax_ = (_Float16)cwA.x, ay_ = (_Float16)cwA.y;  \
          const _Float16 az_ = (_Float16)cwA.z, aw_ = (_Float16)cwA.w;  \
          const _Float16 bx_ = (_Float16)cwB.x, by_ = (_Float16)cwB.y;  \
          const _Float16 bz_ = (_Float16)cwB.z, bw_ = (_Float16)cwB.w;  \
          v8hf rA0 = gA[0]*ax_ + gA[1]*ay_ + gA[2]*az_ + gA[3]*aw_;     \
          v8hf rA1 = gA[4]*ax_ + gA[5]*ay_ + gA[6]*az_ + gA[7]*aw_;     \
          v8hf rB0 = gB[0]*bx_ + gB[1]*by_ + gB[2]*bz_ + gB[3]*bw_;     \
          v8hf rB1 = gB[4]*bx_ + gB[5]*by_ + gB[6]*bz_ + gB[7]*bw_;     \
          _Float16* ap_ = (_Float16*)(AP);                              \
          *(v8hf*)(ap_ + p2 * 64        + (((c2)     ^ (p2 & 7)) << 3)) = rA0; \
          *(v8hf*)(ap_ + p2 * 64        + (((c2 + 4) ^ (p2 & 7)) << 3)) = rA1; \
          *(v8hf*)(ap_ + (p2 + 64) * 64 + (((c2)     ^ (p2 & 7)) << 3)) = rB0; \
          *(v8hf*)(ap_ + (p2 + 64) * 64 + (((c2 + 4) ^ (p2 & 7)) << 3)) = rB1; }

#define STAGE_B8(K0, LB)                                                \
        do { _Pragma("unroll")                                          \
          for (int t = 0; t < 8; ++t) {                                 \
            const int brow = t * 32 + (wv << 3) + (lane >> 3);          \
            const int blc  = (lane & 7) ^ (brow & 7);                   \
            async_copy16(bp + (size_t)brow * KG + (K0) + blc * 8,       \
                         (LB) + ((t * 4 + wv) << 10)); } } while (0)

        // ---- prologue: A0/B0 for step 0, gathers for step 1 in flight
        GATHER16(0, 0)                 // G(0): 16 loads
        STAGE_B8(0, smem + 32768);     // S(0): 8 asyncs  [G16,S8]
        WAIT_VM(8);                    // G(0) ready
        COMBINE16(smem)                // A[0]
        GATHER16(0, 1)                 // G(1)  [S(0)8, G(1)16]
        WAIT_VM(16);                   // S(0) retired
        WAIT_LGKM0;
        BARR;

        char* pa = smem + 16384;       // A[nxt]
        char* pb = smem + 65536;       // B[nxt]
#pragma unroll 1
        for (int ks = 0; ks < 36; ++ks) {
            if (ks < 35) {
                STAGE_B8((ks + 1) << 6, pb);        // [G(ks+1)16, S8]
                WAIT_VM(8);                         // G(ks+1) regs ready
                COMBINE16(pa)                       // A(ks+1) -> A[nxt]
                if (ks < 34) {
                    const int st = ks + 2;
                    GATHER16(st >> 2, st & 3)       // [S8, G16]
                    WAIT_VM(16);                    // S(ks+1) retired
                } else {
                    WAIT_VM(0);                     // S(35) retired
                }
                WAIT_LGKM0;
            }
            BARR;
            pa = (char*)((size_t)smem + 16384 - ((size_t)pa - (size_t)smem));
            pb = (char*)((size_t)smem + 32768 + 65536 + 32768
                         - ((size_t)pb - (size_t)smem) - 32768);
        }
        BARR;                          // epilogue-align; producers exit
#undef GATHER16
#undef COMBINE16
#undef STAGE_B8
    } else {
        // ================= CONSUMER (waves 4-7) =================
        const int cw_id = wv - 4;
        const int wm = cw_id & 1, wn = cw_id >> 1;  // 64px half, 128out half

        v4f acc[4][8];
#pragma unroll
        for (int i = 0; i < 4; ++i)
#pragma unroll
            for (int j = 0; j < 8; ++j) acc[i][j] = (v4f)0.f;

        BARR;                                       // match producer prologue

        char* ca = smem;               // A[cur]
        char* cb = smem + 32768;       // B[cur]
#pragma unroll 1
        for (int ks = 0; ks < 36; ++ks) {
#pragma unroll
            for (int kf = 0; kf < 2; ++kf) {
                v8hf afr[4], bfr[8];
#pragma unroll
                for (int mt = 0; mt < 4; ++mt) {
                    const int row = wm * 64 + mt * 16 + l15;
                    const int pch = (kf * 4 + q) ^ (row & 7);
                    afr[mt] = *(const v8hf*)((_Float16*)ca + row * 64 + pch * 8);
                }
#pragma unroll
                for (int nt = 0; nt < 8; ++nt) {
                    const int row = wn * 128 + nt * 16 + l15;
                    const int pch = (kf * 4 + q) ^ (row & 7);
                    bfr[nt] = *(const v8hf*)((_Float16*)cb + row * 64 + pch * 8);
                }
                __builtin_amdgcn_s_setprio(1);
#pragma unroll
                for (int mt = 0; mt < 4; ++mt)
#pragma unroll
                    for (int nt = 0; nt < 8; ++nt)
                        acc[mt][nt] = __builtin_amdgcn_mfma_f32_16x16x32_f16(
                            afr[mt], bfr[nt], acc[mt][nt], 0, 0, 0);
                __builtin_amdgcn_s_setprio(0);
            }
            WAIT_LGKM0;
            BARR;
            ca = (char*)((size_t)smem + 16384 - ((size_t)ca - (size_t)smem));
            cb = (char*)((size_t)smem + 32768 + 65536 + 32768
                         - ((size_t)cb - (size_t)smem) - 32768);
        }
        BARR;                          // all consumer reads done; epi may alias

        // ---- epilogue: per-wave LDS transpose (wave-local region)
        float* epi = (float*)smem + cw_id * 1104;   // 64 x 17 floats per wave
        const int pg_l = m0 + wm * 64 + lane;
        const int n_l  = pg_l / SPIX;
        float* outp = out + (size_t)n_l * (COUT * SPIX) + (pg_l - n_l * SPIX);

#pragma unroll
        for (int nt = 0; nt < 8; ++nt) {
            const float bv = bias[wn * 128 + nt * 16 + l15];
#pragma unroll
            for (int mt = 0; mt < 4; ++mt)
#pragma unroll
                for (int r = 0; r < 4; ++r)
                    epi[(mt * 16 + q * 4 + r) * 17 + l15] = acc[mt][nt][r] + bv;
#pragma unroll
            for (int oc = 0; oc < 16; ++oc)
                outp[(size_t)(wn * 128 + nt * 16 + oc) * SPIX] = epi[lane * 17 + oc];
        }
    }
}

// ---------- fp32 fallback (round-1 verified, no workspace)
#define BM 64
#define BN 64
#define BKF 32
#define AST 68
#define BST 68
#define CST 65
__global__ __launch_bounds__(256) void mdcn_fallback(
    const float* __restrict__ xs, const float* __restrict__ offs,
    const float* __restrict__ msk, const float* __restrict__ wraw,
    const float* __restrict__ bias, float* __restrict__ out)
{
    __shared__ float smem[BKF * AST + BKF * BST];
    __shared__ int   sBase[4][BM];
    __shared__ float sWgt[4][BM];
    float (*At)[AST] = (float (*)[AST])smem;
    float (*Bt)[BST] = (float (*)[BST])(smem + BKF * AST);
    float (*Cs)[CST] = (float (*)[CST])smem;
    const int tid = threadIdx.x;
    const int m0 = blockIdx.x * BM;
    const int o0 = blockIdx.y * BN;
    const int n  = m0 / SPIX;
    const int s0 = m0 - n * SPIX;
    const int tx = tid & 15, ty = tid >> 4;
    float acc[4][4] = {};
    for (int k = 0; k < 9; ++k) {
        if (tid < BM) {
            const int s = s0 + tid;
            const int h = s / W_;
            const int w = s - h * W_;
            const int kY = k / 3, kX = k - kY * 3;
            const float dy = offs[(size_t)n * (18 * SPIX) + (size_t)(2 * k) * SPIX + s];
            const float dx = offs[(size_t)n * (18 * SPIX) + (size_t)(2 * k + 1) * SPIX + s];
            const float mk = msk[(size_t)n * (9 * SPIX) + (size_t)k * SPIX + s];
            const float py = dy + (float)(kY + h - 1);
            const float px = dx + (float)(kX + w - 1);
            const float fy0 = floorf(py), fx0 = floorf(px);
            const int y0 = (int)fy0, x0 = (int)fx0;
            const float wy1 = py - fy0, wx1 = px - fx0;
            const float wy0 = 1.0f - wy1, wx0 = 1.0f - wx1;
#pragma unroll
            for (int t = 0; t < 4; ++t) {
                const int yi = y0 + (t >> 1), xi = x0 + (t & 1);
                const bool valid = (yi >= 0) & (yi < H_) & (xi >= 0) & (xi < W_);
                const int yc = min(max(yi, 0), H_ - 1);
                const int xc = min(max(xi, 0), W_ - 1);
                float wt = ((t >> 1) ? wy1 : wy0) * ((t & 1) ? wx1 : wx0) * mk;
                sBase[t][tid] = n * (CIN * SPIX) + yc * W_ + xc;
                sWgt[t][tid] = valid ? wt : 0.0f;
            }
        }
        __syncthreads();
        for (int c0 = 0; c0 < CIN; c0 += BKF) {
#pragma unroll
            for (int i = 0; i < 8; ++i) {
                int idx = tid + i * 256;
                int row = idx >> 5, cc = idx & 31;
                int ce = (c0 + cc) * SPIX;
                At[cc][row] = sWgt[0][row] * xs[sBase[0][row] + ce]
                            + sWgt[1][row] * xs[sBase[1][row] + ce]
                            + sWgt[2][row] * xs[sBase[2][row] + ce]
                            + sWgt[3][row] * xs[sBase[3][row] + ce];
            }
#pragma unroll
            for (int i = 0; i < 8; ++i) {
                int idx = tid + i * 256;
                int kf = idx >> 6, o = idx & 63;
                Bt[kf][o] = wraw[(size_t)(o0 + o) * KG + (c0 + kf) * 9 + k];
            }
            __syncthreads();
#pragma unroll
            for (int kf = 0; kf < BKF; ++kf) {
                const float4 a = *(const float4*)&At[kf][ty * 4];
                const float4 b = *(const float4*)&Bt[kf][tx * 4];
                acc[0][0] = fmaf(a.x, b.x, acc[0][0]); acc[0][1] = fmaf(a.x, b.y, acc[0][1]);
                acc[0][2] = fmaf(a.x, b.z, acc[0][2]); acc[0][3] = fmaf(a.x, b.w, acc[0][3]);
                acc[1][0] = fmaf(a.y, b.x, acc[1][0]); acc[1][1] = fmaf(a.y, b.y, acc[1][1]);
                acc[1][2] = fmaf(a.y, b.z, acc[1][2]); acc[1][3] = fmaf(a.y, b.w, acc[1][3]);
                acc[2][0] = fmaf(a.z, b.x, acc[2][0]); acc[2][1] = fmaf(a.z, b.y, acc[2][1]);
                acc[2][2] = fmaf(a.z, b.z, acc[2][2]); acc[2][3] = fmaf(a.z, b.w, acc[2][3]);
                acc[3][0] = fmaf(a.w, b.x, acc[3][0]); acc[3][1] = fmaf(a.w, b.y, acc[3][1]);
                acc[3][2] = fmaf(a.w, b.z, acc[3][2]); acc[3][3] = fmaf(a.w, b.w, acc[3][3]);
            }
            __syncthreads();
        }
    }
#pragma unroll
    for (int i = 0; i < 4; ++i)
#pragma unroll
        for (int j = 0; j < 4; ++j)
            Cs[ty * 4 + i][tx * 4 + j] = acc[i][j] + bias[o0 + tx * 4 + j];
    __syncthreads();
    const int pix = tid & 63, ob = tid >> 6;
    float* outp = out + (size_t)n * COUT * SPIX + s0 + pix;
#pragma unroll
    for (int r = 0; r < 16; ++r) {
        int o = r * 4 + ob;
        outp[(size_t)(o0 + o) * SPIX] = Cs[pix][o];
    }
}

extern "C" void kernel_launch(void* const* d_in, const int* in_sizes, int n_in,
                              void* d_out, int out_size, void* d_ws, size_t ws_size,
                              hipStream_t stream) {
    const float* x    = (const float*)d_in[0];
    const float* offs = (const float*)d_in[1];
    const float* msk  = (const float*)d_in[2];
    const float* w    = (const float*)d_in[3];
    const float* bias = (const float*)d_in[4];
    float* out = (float*)d_out;

    const size_t GUARD_B  = (size_t)GUARD_PX * CIN * sizeof(_Float16);  // 1 MB
    const size_t xb_bytes = (size_t)NB * SPIX * CIN * sizeof(_Float16);
    const size_t bp_bytes = (size_t)KG * COUT * sizeof(_Float16);
    const size_t need     = GUARD_B + xb_bytes + GUARD_B + bp_bytes;

    if (ws_size >= need) {
        _Float16* xb = (_Float16*)((char*)d_ws + GUARD_B);
        _Float16* bp = (_Float16*)((char*)d_ws + GUARD_B + xb_bytes + GUARD_B);
        prep_xw<<<dim3(49, 4, 10), 256, 0, stream>>>(x, w, xb, bp);
        mdcn_fused9<<<dim3(NBLK), 512, 0, stream>>>(xb, offs, msk, bp, bias, out);
    } else {
        mdcn_fallback<<<dim3(MTOT / BM, COUT / BN), 256, 0, stream>>>(
            x, offs, msk, w, bias, out);
    }
}

// Round 10
// 143.158 us; speedup vs baseline: 1.1998x; 1.1731x over previous
//
#include <hip/hip_runtime.h>
#include <math.h>

#define H_ 56
#define W_ 56
#define CIN 256
#define COUT 256
#define NB 8
#define SPIX 3136
#define KG 2304
#define MTOT 25088
#define MT 128
#define NBLK 196   // MTOT / MT
#define GUARD_PX 2048                 // 1 MB guard each side of xb (512 B/px)

typedef _Float16 v8hf __attribute__((ext_vector_type(8)));
typedef float    v4f  __attribute__((ext_vector_type(4)));

#define WAIT_VM(N)  do { asm volatile("s_waitcnt vmcnt(" #N ")" ::: "memory"); \
                         __builtin_amdgcn_sched_barrier(0); } while (0)
#define WAIT_LGKM0  do { asm volatile("s_waitcnt lgkmcnt(0)" ::: "memory"); \
                         __builtin_amdgcn_sched_barrier(0); } while (0)
#define BARR        do { asm volatile("s_barrier" ::: "memory"); } while (0)

__device__ __forceinline__ void async_copy16(const void* g, void* l) {
    __builtin_amdgcn_global_load_lds(
        (const __attribute__((address_space(1))) void*)g,
        (__attribute__((address_space(3))) void*)l, 16, 0, 0);
}

// ---------- merged pre-kernel: z<8: NCHW fp32 -> NHWC f16 (image z)
//            z==8: weight (Cout,Cin,3,3) -> Bp[o][tap*256+c] f16
//            z==9: zero the two 1MB guard bands around xb
__global__ __launch_bounds__(256) void prep_xw(const float* __restrict__ x,
                                               const float* __restrict__ w,
                                               _Float16* __restrict__ xb,
                                               _Float16* __restrict__ bp) {
    __shared__ float tile[64][65];
    const int tid = threadIdx.x;
    if (blockIdx.z < 8) {
        const int n = blockIdx.z, c0 = blockIdx.y * 64, s0 = blockIdx.x * 64;
        const float* xp = x + (size_t)n * CIN * SPIX;
        _Float16* xo = xb + (size_t)n * SPIX * CIN;
#pragma unroll
        for (int i = 0; i < 16; ++i) {
            int idx = tid + i * 256;
            int cr = idx >> 6, sc = idx & 63;
            tile[cr][sc] = xp[(c0 + cr) * SPIX + s0 + sc];
        }
        __syncthreads();
#pragma unroll
        for (int i = 0; i < 16; ++i) {
            int idx = tid + i * 256;
            int sr = idx >> 6, cc = idx & 63;
            xo[(s0 + sr) * CIN + c0 + cc] = (_Float16)tile[cc][sr];
        }
    } else if (blockIdx.z == 8) {
        const int base = (blockIdx.y * 49 + blockIdx.x) * 256 + tid;
        for (int i = base; i < COUT * KG; i += 196 * 256) {
            const int o = i / KG;
            const int rem = i - o * KG;
            const int c = rem / 9;
            const int tap = rem - c * 9;
            bp[(size_t)o * KG + tap * 256 + c] = (_Float16)w[i];
        }
    } else {
        const int gtid = (blockIdx.y * 49 + blockIdx.x) * 256 + tid;
        v8hf* lo = (v8hf*)(xb - (size_t)GUARD_PX * CIN);
        v8hf* hi = (v8hf*)(xb + (size_t)NB * SPIX * CIN);
        const v8hf z = (v8hf)(_Float16)0.f;
        for (int i = gtid; i < 65536; i += 196 * 256) {
            lo[i] = z;
            hi[i] = z;
        }
    }
}

// ---------- bilinear params for ALL 9 taps of this block's 128 px.
// Base UNCLAMPED (corner reads are base-relative); weight-0 corners read
// into zeroed guard bands. Safety clamp only fires when all weights 0.
__device__ __forceinline__ void compute_params(
    const float* __restrict__ offs, const float* __restrict__ msk,
    int m0, int* sS, float4* sW, int tid)
{
    for (int idx = tid; idx < 9 * MT; idx += 512) {
        const int tl = idx >> 7, pl = idx & 127;
        const int pg = m0 + pl;
        const int n  = pg / SPIX;
        const int s  = pg - n * SPIX;
        const int h  = s / W_, w = s - h * W_;
        const int kY = tl / 3, kX = tl - kY * 3;
        const float dy = offs[n * (18 * SPIX) + (2 * tl) * SPIX + s];
        const float dx = offs[n * (18 * SPIX) + (2 * tl + 1) * SPIX + s];
        const float mk = msk[n * (9 * SPIX) + tl * SPIX + s];
        const float py = dy + (float)(kY + h - 1);   // PAD=1,STRIDE=1,DIL=1
        const float px = dx + (float)(kX + w - 1);
        const float fy0 = floorf(py), fx0 = floorf(px);
        const int y0 = (int)fy0, x0 = (int)fx0;
        const float wy1 = py - fy0, wx1 = px - fx0;
        const float wy0 = 1.f - wy1, wx0 = 1.f - wx1;
        const bool yv0 = (y0 >= 0) & (y0 < H_);
        const bool yv1 = (y0 + 1 >= 0) & (y0 + 1 < H_);
        const bool xv0 = (x0 >= 0) & (x0 < W_);
        const bool xv1 = (x0 + 1 >= 0) & (x0 + 1 < W_);
        float4 wt;
        wt.x = (yv0 & xv0) ? wy0 * wx0 * mk : 0.f;
        wt.y = (yv0 & xv1) ? wy0 * wx1 * mk : 0.f;
        wt.z = (yv1 & xv0) ? wy1 * wx0 * mk : 0.f;
        wt.w = (yv1 & xv1) ? wy1 * wx1 * mk : 0.f;
        int base = n * SPIX + y0 * W_ + x0;
        base = min(max(base, -GUARD_PX), NB * SPIX - 58 + GUARD_PX);
        sS[idx] = base * CIN;
        sW[idx] = wt;
    }
}

// ---------- fused deformable-gather + f16 MFMA GEMM (v6, verified 63.5us:
// f16 packed combine + fragment-load hoist on the fused4 skeleton).
// Sync/ledger: one s_barrier per iter, counted vmcnt, A/B double-buffered.
// (1) all 16 MFMA ds_read_b128 issued at iter TOP (latency hidden under
// STAGE+combine); (2) combine in packed f16 (v_pk_fma).
// vmcnt ledger: entry outstanding = gathers(ks+1) 8; +4 stage asyncs;
// vmcnt(4) retires the 8 gathers; +8 gathers(ks+2); MFMA; lgkm0 +
// vmcnt(8) retires the 4 asyncs; s_barrier.
__global__ __launch_bounds__(512, 2) void mdcn_fused6(
    const _Float16* __restrict__ xb,   // NHWC f16 (1MB zeroed guard both sides)
    const float*    __restrict__ offs,
    const float*    __restrict__ msk,
    const _Float16* __restrict__ bp,   // [COUT][KG] tap-major K
    const float*    __restrict__ bias,
    float*          __restrict__ out)
{
    __shared__ __align__(16) char smem[121344];
    // As0 @0 (16K) | As1 @16384 | Bs0 @32768 (32K) | Bs1 @65536
    int*    sS = (int*)(smem + 98304);              // [9*128]
    float4* sW = (float4*)(smem + 102912);          // [9*128]

    const int tid  = threadIdx.x;
    const int lane = tid & 63, wv = tid >> 6;       // 8 waves
    const int wm = wv & 1, wn = wv >> 1;            // m-half 64 px, n-quarter 64
    const int l15 = lane & 15, q = lane >> 4;

    // bijective chunked XCD swizzle: 196 = 8*24 + 4
    const int xcd = blockIdx.x & 7, ib = blockIdx.x >> 3;
    const int wg  = (xcd < 4) ? xcd * 25 + ib : 100 + (xcd - 4) * 24 + ib;
    const int m0  = wg * MT;

    compute_params(offs, msk, m0, sS, sW, tid);

    v4f acc[4][4];
#pragma unroll
    for (int i = 0; i < 4; ++i)
#pragma unroll
        for (int j = 0; j < 4; ++j) acc[i][j] = (v4f)0.f;

    __syncthreads();                                // params visible (once)

    const int pxl = tid >> 2, c2 = tid & 3;         // pixel row, chunk pair
    v8hf ga0, ga1, ga2, ga3, gb0, gb1, gb2, gb3;
    float4 cw;
    v8hf afr[2][4], bfr[2][4];                      // [kf][tile]

#define GATHER(E, KQ)                                                   \
    { const int b_ = sS[E] + ((KQ) << 6) + c2 * 8;                      \
      cw  = sW[E];                                                      \
      ga0 = *(const v8hf*)(xb + b_);                                    \
      ga1 = *(const v8hf*)(xb + b_ + 256);                              \
      ga2 = *(const v8hf*)(xb + b_ + 14336);                            \
      ga3 = *(const v8hf*)(xb + b_ + 14592);                            \
      gb0 = *(const v8hf*)(xb + b_ + 32);                               \
      gb1 = *(const v8hf*)(xb + b_ + 288);                              \
      gb2 = *(const v8hf*)(xb + b_ + 14368);                            \
      gb3 = *(const v8hf*)(xb + b_ + 14624); }

#define COMBINE_STORE(AP)                                               \
    { const _Float16 wx_ = (_Float16)cw.x, wy_ = (_Float16)cw.y;        \
      const _Float16 wz_ = (_Float16)cw.z, ww_ = (_Float16)cw.w;        \
      v8hf r0_ = ga0 * wx_ + ga1 * wy_ + ga2 * wz_ + ga3 * ww_;         \
      v8hf r1_ = gb0 * wx_ + gb1 * wy_ + gb2 * wz_ + gb3 * ww_;         \
      *(v8hf*)((AP) + pxl * 64 + (((c2)     ^ (pxl & 7)) << 3)) = r0_;  \
      *(v8hf*)((AP) + pxl * 64 + (((c2 + 4) ^ (pxl & 7)) << 3)) = r1_; }

#define STAGE_B(K0, LB)                                                 \
    do { _Pragma("unroll")                                              \
      for (int t = 0; t < 4; ++t) {                                     \
        const int brow = t * 64 + (wv << 3) + (lane >> 3);              \
        const int blc  = (lane & 7) ^ (brow & 7);                       \
        async_copy16(bp + (size_t)brow * KG + (K0) + blc * 8,           \
                     (LB) + ((t * 8 + wv) << 10)); } } while (0)

#define LOAD_FRAGS(AB, BB)                                              \
    { _Pragma("unroll")                                                 \
      for (int kf = 0; kf < 2; ++kf) {                                  \
        _Pragma("unroll")                                               \
        for (int mt = 0; mt < 4; ++mt) {                                \
          const int row = wm * 64 + mt * 16 + l15;                      \
          const int pch = (kf * 4 + q) ^ (row & 7);                     \
          afr[kf][mt] = *(const v8hf*)((_Float16*)(AB) + row * 64 + pch * 8); } \
        _Pragma("unroll")                                               \
        for (int nt = 0; nt < 4; ++nt) {                                \
          const int row = wn * 64 + nt * 16 + l15;                      \
          const int pch = (kf * 4 + q) ^ (row & 7);                     \
          bfr[kf][nt] = *(const v8hf*)((_Float16*)(BB) + row * 64 + pch * 8); } } }

#define MFMA_EXEC                                                       \
    { __builtin_amdgcn_s_setprio(1);                                    \
      _Pragma("unroll")                                                 \
      for (int kf = 0; kf < 2; ++kf)                                    \
        _Pragma("unroll")                                               \
        for (int mt = 0; mt < 4; ++mt)                                  \
          _Pragma("unroll")                                             \
          for (int nt = 0; nt < 4; ++nt)                                \
            acc[mt][nt] = __builtin_amdgcn_mfma_f32_16x16x32_f16(       \
                afr[kf][mt], bfr[kf][nt], acc[mt][nt], 0, 0, 0);        \
      __builtin_amdgcn_s_setprio(0); }

    // ---------- prologue: A0/B0 for step 0, gathers for step 1 in flight
    GATHER(pxl, 0)                     // step 0 (tap 0, kq 0)
    COMBINE_STORE((_Float16*)smem)     // -> As0 (implicit vmcnt wait on regs)
    STAGE_B(0, smem + 32768);          // -> Bs0 (4 asyncs)
    GATHER(pxl, 1)                     // step 1 (tap 0, kq 1)
    WAIT_LGKM0;                        // A0 write drained
    WAIT_VM(8);                        // B0 asyncs drained; 8 gathers fly
    BARR;

    char* ac = smem;          char* an = smem + 16384;
    char* bc = smem + 32768;  char* bn = smem + 65536;

#pragma unroll 1
    for (int ks = 0; ks < 36; ++ks) {
        LOAD_FRAGS(ac, bc);            // 16 ds_read_b128 issued FIRST;
                                       // latency hides under stage+combine
        if (ks < 35) {
            STAGE_B((ks + 1) << 6, bn);             // 4 asyncs -> B[nxt]
            WAIT_VM(4);                             // gathers(ks+1) arrived
            COMBINE_STORE((_Float16*)an)            // A(ks+1) -> A[nxt] (pk f16)
            if (ks < 34) {
                const int st = ks + 2;
                GATHER((st >> 2) * MT + pxl, st & 3)  // 8 loads stay in flight
            }
        }

        MFMA_EXEC;                     // frags long since resident

        if (ks < 34) {
            WAIT_LGKM0;                             // A[nxt] writes drained
            WAIT_VM(8);                             // B[nxt] asyncs done
            BARR;
        } else if (ks == 34) {
            WAIT_LGKM0;
            WAIT_VM(0);
            BARR;
        }
        char* t;
        t = ac; ac = an; an = t;
        t = bc; bc = bn; bn = t;
    }
#undef GATHER
#undef COMBINE_STORE
#undef STAGE_B
#undef LOAD_FRAGS
#undef MFMA_EXEC

    // ---- epilogue: per-wave LDS transpose (wave-local region)
    WAIT_LGKM0;
    BARR;                              // all MFMA reads of smem done
    float* epi = (float*)smem + wv * 1104;          // 64 x 17 floats per wave
    const int pg_l = m0 + wm * 64 + lane;
    const int n_l  = pg_l / SPIX;
    float* outp = out + (size_t)n_l * (COUT * SPIX) + (pg_l - n_l * SPIX);

#pragma unroll
    for (int nt = 0; nt < 4; ++nt) {
        const float bv = bias[wn * 64 + nt * 16 + l15];
#pragma unroll
        for (int mt = 0; mt < 4; ++mt)
#pragma unroll
            for (int r = 0; r < 4; ++r)
                epi[(mt * 16 + q * 4 + r) * 17 + l15] = acc[mt][nt][r] + bv;
#pragma unroll
        for (int oc = 0; oc < 16; ++oc)
            outp[(size_t)(wn * 64 + nt * 16 + oc) * SPIX] = epi[lane * 17 + oc];
    }
}

// ---------- fp32 fallback (round-1 verified, no workspace)
#define BM 64
#define BN 64
#define BKF 32
#define AST 68
#define BST 68
#define CST 65
__global__ __launch_bounds__(256) void mdcn_fallback(
    const float* __restrict__ xs, const float* __restrict__ offs,
    const float* __restrict__ msk, const float* __restrict__ wraw,
    const float* __restrict__ bias, float* __restrict__ out)
{
    __shared__ float smem[BKF * AST + BKF * BST];
    __shared__ int   sBase[4][BM];
    __shared__ float sWgt[4][BM];
    float (*At)[AST] = (float (*)[AST])smem;
    float (*Bt)[BST] = (float (*)[BST])(smem + BKF * AST);
    float (*Cs)[CST] = (float (*)[CST])smem;
    const int tid = threadIdx.x;
    const int m0 = blockIdx.x * BM;
    const int o0 = blockIdx.y * BN;
    const int n  = m0 / SPIX;
    const int s0 = m0 - n * SPIX;
    const int tx = tid & 15, ty = tid >> 4;
    float acc[4][4] = {};
    for (int k = 0; k < 9; ++k) {
        if (tid < BM) {
            const int s = s0 + tid;
            const int h = s / W_;
            const int w = s - h * W_;
            const int kY = k / 3, kX = k - kY * 3;
            const float dy = offs[(size_t)n * (18 * SPIX) + (size_t)(2 * k) * SPIX + s];
            const float dx = offs[(size_t)n * (18 * SPIX) + (size_t)(2 * k + 1) * SPIX + s];
            const float mk = msk[(size_t)n * (9 * SPIX) + (size_t)k * SPIX + s];
            const float py = dy + (float)(kY + h - 1);
            const float px = dx + (float)(kX + w - 1);
            const float fy0 = floorf(py), fx0 = floorf(px);
            const int y0 = (int)fy0, x0 = (int)fx0;
            const float wy1 = py - fy0, wx1 = px - fx0;
            const float wy0 = 1.0f - wy1, wx0 = 1.0f - wx1;
#pragma unroll
            for (int t = 0; t < 4; ++t) {
                const int yi = y0 + (t >> 1), xi = x0 + (t & 1);
                const bool valid = (yi >= 0) & (yi < H_) & (xi >= 0) & (xi < W_);
                const int yc = min(max(yi, 0), H_ - 1);
                const int xc = min(max(xi, 0), W_ - 1);
                float wt = ((t >> 1) ? wy1 : wy0) * ((t & 1) ? wx1 : wx0) * mk;
                sBase[t][tid] = n * (CIN * SPIX) + yc * W_ + xc;
                sWgt[t][tid] = valid ? wt : 0.0f;
            }
        }
        __syncthreads();
        for (int c0 = 0; c0 < CIN; c0 += BKF) {
#pragma unroll
            for (int i = 0; i < 8; ++i) {
                int idx = tid + i * 256;
                int row = idx >> 5, cc = idx & 31;
                int ce = (c0 + cc) * SPIX;
                At[cc][row] = sWgt[0][row] * xs[sBase[0][row] + ce]
                            + sWgt[1][row] * xs[sBase[1][row] + ce]
                            + sWgt[2][row] * xs[sBase[2][row] + ce]
                            + sWgt[3][row] * xs[sBase[3][row] + ce];
            }
#pragma unroll
            for (int i = 0; i < 8; ++i) {
                int idx = tid + i * 256;
                int kf = idx >> 6, o = idx & 63;
                Bt[kf][o] = wraw[(size_t)(o0 + o) * KG + (c0 + kf) * 9 + k];
            }
            __syncthreads();
#pragma unroll
            for (int kf = 0; kf < BKF; ++kf) {
                const float4 a = *(const float4*)&At[kf][ty * 4];
                const float4 b = *(const float4*)&Bt[kf][tx * 4];
                acc[0][0] = fmaf(a.x, b.x, acc[0][0]); acc[0][1] = fmaf(a.x, b.y, acc[0][1]);
                acc[0][2] = fmaf(a.x, b.z, acc[0][2]); acc[0][3] = fmaf(a.x, b.w, acc[0][3]);
                acc[1][0] = fmaf(a.y, b.x, acc[1][0]); acc[1][1] = fmaf(a.y, b.y, acc[1][1]);
                acc[1][2] = fmaf(a.y, b.z, acc[1][2]); acc[1][3] = fmaf(a.y, b.w, acc[1][3]);
                acc[2][0] = fmaf(a.z, b.x, acc[2][0]); acc[2][1] = fmaf(a.z, b.y, acc[2][1]);
                acc[2][2] = fmaf(a.z, b.z, acc[2][2]); acc[2][3] = fmaf(a.z, b.w, acc[2][3]);
                acc[3][0] = fmaf(a.w, b.x, acc[3][0]); acc[3][1] = fmaf(a.w, b.y, acc[3][1]);
                acc[3][2] = fmaf(a.w, b.z, acc[3][2]); acc[3][3] = fmaf(a.w, b.w, acc[3][3]);
            }
            __syncthreads();
        }
    }
#pragma unroll
    for (int i = 0; i < 4; ++i)
#pragma unroll
        for (int j = 0; j < 4; ++j)
            Cs[ty * 4 + i][tx * 4 + j] = acc[i][j] + bias[o0 + tx * 4 + j];
    __syncthreads();
    const int pix = tid & 63, ob = tid >> 6;
    float* outp = out + (size_t)n * COUT * SPIX + s0 + pix;
#pragma unroll
    for (int r = 0; r < 16; ++r) {
        int o = r * 4 + ob;
        outp[(size_t)(o0 + o) * SPIX] = Cs[pix][o];
    }
}

extern "C" void kernel_launch(void* const* d_in, const int* in_sizes, int n_in,
                              void* d_out, int out_size, void* d_ws, size_t ws_size,
                              hipStream_t stream) {
    const float* x    = (const float*)d_in[0];
    const float* offs = (const float*)d_in[1];
    const float* msk  = (const float*)d_in[2];
    const float* w    = (const float*)d_in[3];
    const float* bias = (const float*)d_in[4];
    float* out = (float*)d_out;

    const size_t GUARD_B  = (size_t)GUARD_PX * CIN * sizeof(_Float16);  // 1 MB
    const size_t xb_bytes = (size_t)NB * SPIX * CIN * sizeof(_Float16);
    const size_t bp_bytes = (size_t)KG * COUT * sizeof(_Float16);
    const size_t need     = GUARD_B + xb_bytes + GUARD_B + bp_bytes;

    if (ws_size >= need) {
        _Float16* xb = (_Float16*)((char*)d_ws + GUARD_B);
        _Float16* bp = (_Float16*)((char*)d_ws + GUARD_B + xb_bytes + GUARD_B);
        prep_xw<<<dim3(49, 4, 10), 256, 0, stream>>>(x, w, xb, bp);
        mdcn_fused6<<<dim3(NBLK), 512, 0, stream>>>(xb, offs, msk, bp, bias, out);
    } else {
        mdcn_fallback<<<dim3(MTOT / BM, COUT / BN), 256, 0, stream>>>(
            x, offs, msk, w, bias, out);
    }
}